// Round 3
// baseline (1679.345 us; speedup 1.0000x reference)
//
#include <hip/hip_runtime.h>

typedef unsigned short u16;
typedef unsigned int   u32;
typedef _Float16       f16;

#define B_SZ 2048
#define S_SZ 1024
#define N3   3072
#define F_SZ 50
#define NK   32          // K in blocks of 32

typedef f16    f16x8 __attribute__((ext_vector_type(8)));
typedef float  f32x4 __attribute__((ext_vector_type(4)));
typedef u32    u32x4 __attribute__((ext_vector_type(4)));

// Fragment tiling for mfma_f32_16x16x32_f16 operands (layout verified by the
// working v1 LDS path): tile FT[R][K] is 1 KB; slot[lane = quad*16+lrow][e]
// = X[R*16 + lrow][K*32 + quad*8 + e].  A wave loads one fragment as a single
// coalesced 1KB global_load_dwordx4 (lane*16B).  f16 linear index:
//   ((R*NK + K)*64 + lane)*8 + e

// ---------------------------------------------------------------------------
// Mx[2][3072] = W_emb @ W_gru[0:1024, :]  (split-K + atomics; Mx pre-zeroed)
__global__ __launch_bounds__(256) void make_mx(
    const float* __restrict__ We, const float* __restrict__ Wg,
    float* __restrict__ Mx)
{
    int j  = blockIdx.x * 256 + threadIdx.x;
    int k0 = blockIdx.y * 64;
    float s0 = 0.f, s1 = 0.f;
    #pragma unroll 4
    for (int k = k0; k < k0 + 64; k++) {
        float w = Wg[(size_t)k * N3 + j];
        s0 += We[k] * w;
        s1 += We[S_SZ + k] * w;
    }
    atomicAdd(&Mx[j], s0);
    atomicAdd(&Mx[N3 + j], s1);
}

// ---------------------------------------------------------------------------
// WtF = fp16(W_gru[1024+k][n]) in fragment layout [n/16][k/32][64][8]
__global__ __launch_bounds__(256) void transpose_w(
    const float* __restrict__ Wg, f16* __restrict__ WtF)
{
    __shared__ float tile[32][33];
    int n0 = blockIdx.x * 32, k0 = blockIdx.y * 32;
    int c = threadIdx.x & 31, r = threadIdx.x >> 5;
    #pragma unroll
    for (int s = 0; s < 4; s++) {
        int rr = r + s * 8;
        tile[rr][c] = Wg[(size_t)(S_SZ + k0 + rr) * N3 + n0 + c];
    }
    __syncthreads();
    #pragma unroll
    for (int s = 0; s < 4; s++) {
        int rr = r + s * 8;
        int n = n0 + rr, k = k0 + c;
        size_t o = ((size_t)(n >> 4) * NK + (k >> 5)) * 512
                 + (((k >> 3) & 3) * 16 + (n & 15)) * 8 + (k & 7);
        WtF[o] = (f16)tile[c][rr];
    }
}

// ---------------------------------------------------------------------------
// gemm_step v4: LDS-free fragment GEMM.
//   Operands pre-tiled in MFMA fragment layout -> each fragment is one
//   coalesced 1KB dwordx4 wave-load from L2/L3.  No LDS, no barriers, no
//   lockstep: compiler schedules counted vmcnt waits over a static 2-deep
//   register double-buffer.  Wave tile 64x96 (acc[4][6]; 24 MFMA / 10 loads
//   per K32-step).  Block = 2x2 waves (128x192); grid 256 = 1 block/CU,
//   1 wave/SIMD (MFMA ILP from 24 independent accumulators saturates the
//   matrix pipe).  XCD mapping: 4mt x 8nt rectangle per XCD -> A 1MB + B 3MB
//   ~= one XCD L2.
__global__ __launch_bounds__(256, 1) void gemm_step(
    const f16* __restrict__ WtF,   // [192][32][64][8] fragment layout
    const f16* __restrict__ hhF,   // [128][32][64][8] fragment layout
    const float* __restrict__ Mx,  // [2][3072]
    const float* __restrict__ act, // [2048][50][2]
    f16* __restrict__ parts,       // [2048][3072] f16
    int t)
{
    const int bid  = blockIdx.x;
    const int xcd  = bid & 7, idx = bid >> 3;       // 32 blocks per XCD slice
    const int mt   = (xcd & 3) * 4 + (idx & 3);     // 0..15 (128-row tiles)
    const int nt   = (xcd >> 2) * 8 + (idx >> 2);   // 0..15 (192-col tiles)
    const int lane = threadIdx.x & 63;
    const int wave = threadIdx.x >> 6;
    const int m0   = mt * 128 + (wave >> 1) * 64;
    const int n0   = nt * 192 + (wave & 1) * 96;
    const int R0   = m0 >> 4;                       // 4 fragment rows (A)
    const int C0   = n0 >> 4;                       // 6 fragment rows (B)
    const int quad = lane >> 4, lrow = lane & 15;

    const f16* Ab = hhF + (size_t)R0 * NK * 512 + lane * 8;
    const f16* Bb = WtF + (size_t)C0 * NK * 512 + lane * 8;

    f32x4 acc[4][6];
    #pragma unroll
    for (int i = 0; i < 4; i++)
        #pragma unroll
        for (int j = 0; j < 6; j++)
            acc[i][j] = (f32x4){0.f, 0.f, 0.f, 0.f};

    f16x8 A0[4], A1[4], B0[6], B1[6];

    auto lda = [&](f16x8* A, int kb) {
        #pragma unroll
        for (int i = 0; i < 4; i++)
            A[i] = __builtin_bit_cast(f16x8,
                *(const u32x4*)(Ab + ((i * NK + kb) << 9)));
    };
    auto ldb = [&](f16x8* Bv, int kb) {
        #pragma unroll
        for (int j = 0; j < 6; j++)
            Bv[j] = __builtin_bit_cast(f16x8,
                *(const u32x4*)(Bb + ((j * NK + kb) << 9)));
    };

    lda(A0, 0); ldb(B0, 0);          // prologue: 2-deep prefetch
    lda(A1, 1); ldb(B1, 1);

    for (int kb2 = 0; kb2 < NK / 2; kb2++) {
        #pragma unroll
        for (int i = 0; i < 4; i++)
            #pragma unroll
            for (int j = 0; j < 6; j++)
                acc[i][j] = __builtin_amdgcn_mfma_f32_16x16x32_f16(
                    A0[i], B0[j], acc[i][j], 0, 0, 0);
        if (kb2 < NK / 2 - 1) { lda(A0, 2 * kb2 + 2); ldb(B0, 2 * kb2 + 2); }
        #pragma unroll
        for (int i = 0; i < 4; i++)
            #pragma unroll
            for (int j = 0; j < 6; j++)
                acc[i][j] = __builtin_amdgcn_mfma_f32_16x16x32_f16(
                    A1[i], B1[j], acc[i][j], 0, 0, 0);
        if (kb2 < NK / 2 - 1) { lda(A1, 2 * kb2 + 3); ldb(B1, 2 * kb2 + 3); }
    }

    // epilogue: + act @ Mx, write parts (f16), layout unchanged
    float mx0[6], mx1[6];
    #pragma unroll
    for (int j = 0; j < 6; j++) {
        int n = n0 + j * 16 + lrow;
        mx0[j] = Mx[n];
        mx1[j] = Mx[N3 + n];
    }
    #pragma unroll
    for (int i = 0; i < 4; i++) {
        #pragma unroll
        for (int rr = 0; rr < 4; rr++) {
            int m = m0 + i * 16 + quad * 4 + rr;
            float a0 = act[((size_t)m * F_SZ + t) * 2 + 0];
            float a1 = act[((size_t)m * F_SZ + t) * 2 + 1];
            #pragma unroll
            for (int j = 0; j < 6; j++) {
                int n = n0 + j * 16 + lrow;
                parts[(size_t)m * N3 + n] =
                    (f16)(acc[i][j][rr] + a0 * mx0[j] + a1 * mx1[j]);
            }
        }
    }
}

// ---------------------------------------------------------------------------
// LayerNorm + gates + h update. 2 rows/block; thread owns 8 units.
// h state written in FRAGMENT layout (so gemm reads it fragment-direct);
// fp32 h written linear to d_out at t=49.
__global__ __launch_bounds__(256) void ln_gate_step(
    const f16* __restrict__ parts,
    const float* __restrict__ gamma,
    const float* __restrict__ beta,
    f16* __restrict__ hh,           // fp16 state, fragment layout
    float* __restrict__ hout,       // d_out h region (written only at t=49)
    int t)
{
    const int tid = threadIdx.x;
    const int r2  = tid >> 7;                 // 0..1
    const int tl  = tid & 127;                // owns units tl*8..tl*8+7
    const int row = blockIdx.x * 2 + r2;
    const f16* p = parts + (size_t)row * N3 + tl * 8;

    float v[24];
    float s = 0.f, ss = 0.f;
    #pragma unroll
    for (int g = 0; g < 3; g++) {
        f16x8 x = *(const f16x8*)(p + g * S_SZ);
        #pragma unroll
        for (int e = 0; e < 8; e++) {
            float f = (float)x[e];
            v[g * 8 + e] = f;
            s += f; ss += f * f;
        }
    }
    #pragma unroll
    for (int o = 1; o < 64; o <<= 1) {
        s  += __shfl_xor(s, o);
        ss += __shfl_xor(ss, o);
    }
    __shared__ float red[8];
    int wave = tid >> 6, lane = tid & 63;
    if (lane == 0) { red[wave] = s; red[4 + wave] = ss; }
    __syncthreads();
    float S  = red[r2 * 2] + red[r2 * 2 + 1];
    float SS = red[4 + r2 * 2] + red[4 + r2 * 2 + 1];
    float mean = S * (1.f / N3);
    float var  = SS * (1.f / N3) - mean * mean;
    float rstd = rsqrtf(var + 1e-3f);

    float nv[24];
    #pragma unroll
    for (int g = 0; g < 3; g++) {
        f32x4 g0 = *(const f32x4*)(gamma + g * S_SZ + tl * 8);
        f32x4 g1 = *(const f32x4*)(gamma + g * S_SZ + tl * 8 + 4);
        f32x4 b0 = *(const f32x4*)(beta  + g * S_SZ + tl * 8);
        f32x4 b1 = *(const f32x4*)(beta  + g * S_SZ + tl * 8 + 4);
        #pragma unroll
        for (int e = 0; e < 4; e++) {
            nv[g * 8 + e]     = (v[g * 8 + e]     - mean) * rstd * g0[e] + b0[e];
            nv[g * 8 + e + 4] = (v[g * 8 + e + 4] - mean) * rstd * g1[e] + b1[e];
        }
    }

    // fragment address of this thread's 8 h units:
    //   R = row>>4, K = tl>>2, lane = (tl&3)*16 + (row&15)
    size_t hfrag = ((size_t)(row >> 4) * NK + (tl >> 2)) * 512
                 + ((size_t)((tl & 3) * 16 + (row & 15))) * 8;
    f16x8 hp = *(const f16x8*)(hh + hfrag);
    f16x8 hs;
    f32x4 ho0, ho1;
    #pragma unroll
    for (int e = 0; e < 8; e++) {
        float rg = 1.f / (1.f + __expf(-nv[e]));
        float x  = rg * nv[8 + e];
        float tt = __expf(-2.f * fabsf(x));            // stable fast tanh
        float cg = __builtin_copysignf((1.f - tt) / (1.f + tt), x);
        float ug = 1.f / (1.f + __expf(-(nv[16 + e] - 1.f)));
        float hv = ug * cg + (1.f - ug) * (float)hp[e];
        hs[e] = (f16)hv;
        if (e < 4) ho0[e] = hv; else ho1[e - 4] = hv;
    }
    *(f16x8*)(hh + hfrag) = hs;
    if (t == F_SZ - 1) {
        size_t hbase = (size_t)row * S_SZ + tl * 8;   // linear fp32 out
        *(f32x4*)(hout + hbase)     = ho0;
        *(f32x4*)(hout + hbase + 4) = ho1;
    }
}

// ---------------------------------------------------------------------------
// out[B*S + row*2 + {0,1}] = h_row @ W_dec + b_dec   (fp32)
__global__ __launch_bounds__(256) void final_out(
    const float* __restrict__ h, const float* __restrict__ Wd,
    const float* __restrict__ bd, float* __restrict__ out)
{
    int row = blockIdx.x * 4 + (threadIdx.x >> 6);
    int lane = threadIdx.x & 63;
    const float* hr = h + (size_t)row * S_SZ;
    float s0 = 0.f, s1 = 0.f;
    #pragma unroll
    for (int k = lane; k < S_SZ; k += 64) {
        float x = hr[k];
        s0 += x * Wd[k * 2];
        s1 += x * Wd[k * 2 + 1];
    }
    #pragma unroll
    for (int o = 32; o > 0; o >>= 1) {
        s0 += __shfl_down(s0, o);
        s1 += __shfl_down(s1, o);
    }
    if (lane == 0) {
        out[(size_t)B_SZ * S_SZ + row * 2 + 0] = s0 + bd[0];
        out[(size_t)B_SZ * S_SZ + row * 2 + 1] = s1 + bd[1];
    }
}

// ---------------------------------------------------------------------------
extern "C" void kernel_launch(void* const* d_in, const int* in_sizes, int n_in,
                              void* d_out, int out_size, void* d_ws, size_t ws_size,
                              hipStream_t stream)
{
    const float* act = (const float*)d_in[0]; // [2048][50][2]
    const float* We  = (const float*)d_in[1]; // [2][1024]
    const float* Wg  = (const float*)d_in[2]; // [2048][3072]
    const float* lng = (const float*)d_in[3]; // [3072]
    const float* lnb = (const float*)d_in[4]; // [3072]
    const float* Wd  = (const float*)d_in[5]; // [1024][2]
    const float* bd  = (const float*)d_in[6]; // [2]
    float* out = (float*)d_out;               // fp32 [B*S h_last][B*2 outputs]

    char* ws = (char*)d_ws;                   // ws_size = 256 MiB
    f16*   Wt    = (f16*)ws;                  //  6,291,456 B (fragment layout)
    float* Mx    = (float*)(ws + 6291456);    //     24,576 B
    f16*   hh    = (f16*)(ws + 6316032);      //  4,194,304 B (fragment layout)
    f16*   parts = (f16*)(ws + 10510336);     // 12,582,912 B

    hipMemsetAsync(hh, 0, (size_t)B_SZ * S_SZ * 2, stream);
    hipMemsetAsync(Mx, 0, 2 * N3 * 4, stream);
    make_mx<<<dim3(N3 / 256, 16), 256, 0, stream>>>(We, Wg, Mx);
    transpose_w<<<dim3(N3 / 32, S_SZ / 32), 256, 0, stream>>>(Wg, Wt);

    for (int t = 0; t < F_SZ; t++) {
        gemm_step<<<dim3(256), 256, 0, stream>>>(Wt, hh, Mx, act, parts, t);
        ln_gate_step<<<B_SZ / 2, 256, 0, stream>>>(parts, lng, lnb, hh, out, t);
    }
    final_out<<<B_SZ / 4, 256, 0, stream>>>(out, Wd, bd, out);
}